// Round 3
// baseline (638.615 us; speedup 1.0000x reference)
//
#include <hip/hip_runtime.h>
#include <hip/hip_bf16.h>

// Shapes (fixed by setup_inputs): BC=128, H=4, N=1024, d=64, l=16, B=4, C=32,
// C_ch=32, TC=144, r=8. All float tensors are FLOAT32 (per reference).
typedef unsigned short ushort_t;

__device__ __forceinline__ float bf2f(ushort_t u) {
    return __uint_as_float(((unsigned int)u) << 16);
}
__device__ __forceinline__ ushort_t f2bf(float f) {
    __hip_bfloat16 h = __float2bfloat16(f);
    return *reinterpret_cast<ushort_t*>(&h);
}

// ---------------- pq = slots[0] @ W^T, reshaped to [h][l][d] ----------------
__global__ void k_pq(const float* __restrict__ slots,
                     const float* __restrict__ W,
                     float* __restrict__ pq) {
    __shared__ float SL[4096];     // slots[l][i] 16x256
    int j = threadIdx.x;           // 0..255 = h*64+d
#pragma unroll
    for (int i = 0; i < 16; ++i) SL[j + i * 256] = slots[j + i * 256];
    __syncthreads();
    float acc[16];
#pragma unroll
    for (int l = 0; l < 16; ++l) acc[l] = 0.f;
    const float4* wr = (const float4*)(W + j * 256);
    for (int g = 0; g < 64; ++g) {
        float4 wv = wr[g];
#pragma unroll
        for (int l = 0; l < 16; ++l) {
            const float* sl = &SL[l * 256 + g * 4];
            acc[l] += wv.x * sl[0] + wv.y * sl[1] + wv.z * sl[2] + wv.w * sl[3];
        }
    }
    int h = j >> 6, d = j & 63;
#pragma unroll
    for (int l = 0; l < 16; ++l) pq[(h * 16 + l) * 64 + d] = acc[l];
}

// ---------------- mu_flat[l][c*32+dd], mu_sqnorm[l] ----------------
__global__ void k_mu(const float* __restrict__ mu,
                     const int* __restrict__ cidx,
                     float* __restrict__ mu_flat,
                     float* __restrict__ mu_sq) {
    int l = blockIdx.x;            // 16 blocks
    __shared__ float U[256];       // [c][r] 32x8
    __shared__ float utu[64];
    int t = threadIdx.x;
    {
        int c = t >> 3, r = t & 7;
        U[t] = mu[(l * 144 + cidx[c]) * 8 + r];
    }
    __syncthreads();
#pragma unroll
    for (int i = 0; i < 4; ++i) {
        int e = t + i * 256;
        int c = e >> 5, dd = e & 31;
        float acc = 0.f;
#pragma unroll
        for (int r = 0; r < 8; ++r) acc += U[c * 8 + r] * U[dd * 8 + r];
        mu_flat[l * 1024 + e] = acc;
    }
    if (t < 64) {
        int r = t >> 3, s = t & 7;
        float acc = 0.f;
        for (int c = 0; c < 32; ++c) acc += U[c * 8 + r] * U[c * 8 + s];
        utu[t] = acc;
    }
    __syncthreads();
    if (t == 0) {
        float acc = 0.f;
        for (int i = 0; i < 64; ++i) acc += utu[i] * utu[i];
        mu_sq[l] = acc;
    }
}

// ---------------- dist[bs][l][n] ----------------
// grid = ((bs*4+lg)*4+chunk) = 64 blocks; 4 slots per block; thread = one n
__global__ __launch_bounds__(256) void k_dist(const float* __restrict__ Ln,
                                              const float* __restrict__ mu_flat,
                                              const float* __restrict__ mu_sq,
                                              float* __restrict__ dist) {
    int blk = blockIdx.x;
    int chunk = blk & 3;
    int lg = (blk >> 2) & 3;       // slot group: l = lg*4 .. lg*4+3
    int bs = blk >> 4;
    __shared__ float MF[4][1024];
    int t = threadIdx.x;
#pragma unroll
    for (int i = 0; i < 16; ++i) {
        int e = t + i * 256;
        MF[e >> 10][e & 1023] = mu_flat[(lg * 4 + (e >> 10)) * 1024 + (e & 1023)];
    }
    __syncthreads();
    int n = chunk * 256 + t;
    const float4* lr = (const float4*)(Ln + ((size_t)(bs * 1024 + n)) * 1024);
    float lsq = 0.f;
    float cr[4] = {0.f, 0.f, 0.f, 0.f};
    for (int g = 0; g < 256; ++g) {
        float4 lv = lr[g];
        lsq += lv.x * lv.x + lv.y * lv.y + lv.z * lv.z + lv.w * lv.w;
#pragma unroll
        for (int ll = 0; ll < 4; ++ll) {
            const float* mf = &MF[ll][g * 4];
            cr[ll] += lv.x * mf[0] + lv.y * mf[1] + lv.z * mf[2] + lv.w * mf[3];
        }
    }
#pragma unroll
    for (int ll = 0; ll < 4; ++ll) {
        int l = lg * 4 + ll;
        float d2 = lsq + mu_sq[l] - 2.f * cr[ll];
        dist[(bs * 16 + l) * 1024 + n] = sqrtf(fmaxf(d2, 0.f));
    }
}

// ---------------- pack: scores -> softmax -> packed ----------------
// grid = bc*4+h = 512 blocks, 1024 threads: thread t owns key/value row n=t.
// Scores in registers; post-softmax probabilities stored bf16 in LDS (32KB).
// Total LDS ~53KB.
__global__ __launch_bounds__(1024) void k_pack2(const float* __restrict__ kt,
                                                const float* __restrict__ vt,
                                                const float* __restrict__ pq,
                                                const float* __restrict__ dist,
                                                const float* __restrict__ beta_p,
                                                float* __restrict__ packed) {
    int bc = blockIdx.x >> 2, h = blockIdx.x & 3;
    int bs = bc >> 5;                      // bc / C, C==32
    __shared__ __align__(16) float PQ[1024];           // 4KB
    __shared__ __align__(16) ushort_t PB[16 * 1024];   // 32KB post-softmax p (bf16)
    __shared__ __align__(16) float VST[64 * 64];       // 16KB v chunk (64 rows, f32)
    __shared__ float wred[16 * 16];                    // [l][wave]
    __shared__ float gred[16];
    int t = threadIdx.x;                   // = n
    int lane = t & 63, w = t >> 6;         // 16 waves
    PQ[t] = pq[h * 1024 + t];
    float beta = beta_p[0];
    __syncthreads();

    // scores for all 16 slots, accumulated in registers with chunked k-loads
    const size_t base = ((size_t)blockIdx.x) * 65536;  // (bc*4+h)*1024*64
    const float4* kr = (const float4*)(kt + base + (size_t)t * 64);
    float sc[16];
#pragma unroll
    for (int l = 0; l < 16; ++l) sc[l] = 0.f;
    for (int g = 0; g < 16; ++g) {
        float4 kv = kr[g];
#pragma unroll
        for (int l = 0; l < 16; ++l) {
            const float* pql = &PQ[l * 64 + g * 4];
            sc[l] += kv.x * pql[0] + kv.y * pql[1] + kv.z * pql[2] + kv.w * pql[3];
        }
    }
#pragma unroll
    for (int l = 0; l < 16; ++l)
        sc[l] = 0.125f * sc[l] - beta * dist[(bs * 16 + l) * 1024 + t];

    // block-wide max per l
#pragma unroll
    for (int l = 0; l < 16; ++l) {
        float m = sc[l];
#pragma unroll
        for (int off = 32; off >= 1; off >>= 1) m = fmaxf(m, __shfl_xor(m, off));
        if (lane == 0) wred[l * 16 + w] = m;
    }
    __syncthreads();
    if (t < 16) {
        float m = -1e30f;
#pragma unroll
        for (int w2 = 0; w2 < 16; ++w2) m = fmaxf(m, wred[t * 16 + w2]);
        gred[t] = m;
    }
    __syncthreads();

    // exp + block-wide sum per l
    float ex[16];
#pragma unroll
    for (int l = 0; l < 16; ++l) {
        ex[l] = __expf(sc[l] - gred[l]);
        float s = ex[l];
#pragma unroll
        for (int off = 32; off >= 1; off >>= 1) s += __shfl_xor(s, off);
        if (lane == 0) wred[l * 16 + w] = s;
    }
    __syncthreads();
    if (t < 16) {
        float s = 0.f;
#pragma unroll
        for (int w2 = 0; w2 < 16; ++w2) s += wred[t * 16 + w2];
        gred[t] = 1.f / s;
    }
    __syncthreads();
#pragma unroll
    for (int l = 0; l < 16; ++l) PB[l * 1024 + t] = f2bf(ex[l] * gred[l]);
    __syncthreads();

    // packed[l][d] = sum_n p[l][n] * v[n][d]; v staged in 16 LDS chunks of 64 rows
    const float4* vr = (const float4*)(vt + base);
    int l = w, d = lane;                   // wave w handles slot l=w, lanes = d
    float acc = 0.f;
    for (int ch = 0; ch < 16; ++ch) {
        __syncthreads();
        ((float4*)VST)[t] = vr[ch * 1024 + t];
        __syncthreads();
        const ushort_t* pb = &PB[l * 1024 + ch * 64];
#pragma unroll 4
        for (int j = 0; j < 64; ++j) acc += bf2f(pb[j]) * VST[j * 64 + d];
    }
    packed[((size_t)blockIdx.x) * 1024 + t] = acc;
}

// ---------------- processed = sdpa(packed, packed, packed) ----------------
__global__ void k_proc(const float* __restrict__ packed, float* __restrict__ proc) {
    int bh = blockIdx.x;           // 512 blocks
    __shared__ float P[1024];
    __shared__ float A[256];
    int t = threadIdx.x;
#pragma unroll
    for (int i = 0; i < 4; ++i) P[t + i * 256] = packed[(size_t)bh * 1024 + t + i * 256];
    __syncthreads();
    {
        int i = t >> 4, j = t & 15;
        float acc = 0.f;
#pragma unroll
        for (int dd = 0; dd < 64; ++dd) acc += P[i * 64 + dd] * P[j * 64 + dd];
        A[t] = acc * 0.125f;
    }
    __syncthreads();
    if (t < 16) {
        float m = -1e30f;
#pragma unroll
        for (int j = 0; j < 16; ++j) m = fmaxf(m, A[t * 16 + j]);
        float s = 0.f;
#pragma unroll
        for (int j = 0; j < 16; ++j) { float e = __expf(A[t * 16 + j] - m); A[t * 16 + j] = e; s += e; }
        float inv = 1.f / s;
#pragma unroll
        for (int j = 0; j < 16; ++j) A[t * 16 + j] *= inv;
    }
    __syncthreads();
#pragma unroll
    for (int i = 0; i < 4; ++i) {
        int e = t + i * 256;
        int r = e >> 6, d = e & 63;
        float acc = 0.f;
#pragma unroll
        for (int j = 0; j < 16; ++j) acc += A[r * 16 + j] * P[j * 64 + d];
        proc[(size_t)bh * 1024 + e] = acc;
    }
}

// ---------------- out = sdpa(q, processed, processed) ----------------
// grid = bh*4+chunk = 2048 blocks, thread = one q row
__global__ __launch_bounds__(256) void k_final(const float* __restrict__ qt,
                                               const float* __restrict__ proc,
                                               float* __restrict__ out) {
    int bh = blockIdx.x >> 2, ch = blockIdx.x & 3;
    __shared__ float P[1024];
    int t = threadIdx.x;
#pragma unroll
    for (int i = 0; i < 4; ++i) P[t + i * 256] = proc[(size_t)bh * 1024 + t + i * 256];
    __syncthreads();
    int n = ch * 256 + t;
    const float4* qr = (const float4*)(qt + ((size_t)bh * 1024 + n) * 64);
    float qf[64];
#pragma unroll
    for (int g = 0; g < 16; ++g) {
        float4 qv = qr[g];
        qf[g * 4 + 0] = qv.x; qf[g * 4 + 1] = qv.y;
        qf[g * 4 + 2] = qv.z; qf[g * 4 + 3] = qv.w;
    }
    float sj[16];
    float m = -1e30f;
#pragma unroll
    for (int j = 0; j < 16; ++j) {
        float acc = 0.f;
#pragma unroll
        for (int dd = 0; dd < 64; ++dd) acc += qf[dd] * P[j * 64 + dd];
        sj[j] = acc * 0.125f;
        m = fmaxf(m, sj[j]);
    }
    float s = 0.f;
#pragma unroll
    for (int j = 0; j < 16; ++j) { sj[j] = __expf(sj[j] - m); s += sj[j]; }
    float inv = 1.f / s;
#pragma unroll
    for (int j = 0; j < 16; ++j) sj[j] *= inv;
    float4* orow = (float4*)(out + ((size_t)bh * 1024 + n) * 64);
#pragma unroll
    for (int g = 0; g < 16; ++g) {
        float4 pk;
        float* pp = (float*)&pk;
#pragma unroll
        for (int kk = 0; kk < 4; ++kk) {
            int d = g * 4 + kk;
            float acc = 0.f;
#pragma unroll
            for (int j = 0; j < 16; ++j) acc += sj[j] * P[j * 64 + d];
            pp[kk] = acc;
        }
        orow[g] = pk;
    }
}

extern "C" void kernel_launch(void* const* d_in, const int* in_sizes, int n_in,
                              void* d_out, int out_size, void* d_ws, size_t ws_size,
                              hipStream_t stream) {
    const float* q     = (const float*)d_in[0];
    const float* k     = (const float*)d_in[1];
    const float* v     = (const float*)d_in[2];
    const float* Ln    = (const float*)d_in[3];
    const float* slots = (const float*)d_in[4];
    const float* W     = (const float*)d_in[5];
    const float* mu    = (const float*)d_in[6];
    const float* beta  = (const float*)d_in[7];
    const int* cidx    = (const int*)d_in[8];
    // d_in[9] is C (==32), hard-coded in kernels.

    float* ws     = (float*)d_ws;
    float* pq     = ws;                 //   4096 f32
    float* muf    = ws + 4096;          //  16384 f32
    float* musq   = ws + 20480;         //     16 f32
    float* dist   = ws + 20496;         //  65536 f32
    float* packed = ws + 86032;         // 524288 f32
    float* proc   = ws + 610320;        // 524288 f32  (total ~4.5 MB)

    k_pq   <<<1,    256, 0, stream>>>(slots, W, pq);
    k_mu   <<<16,   256, 0, stream>>>(mu, cidx, muf, musq);
    k_dist <<<64,   256, 0, stream>>>(Ln, muf, musq, dist);
    k_pack2<<<512, 1024, 0, stream>>>(k, v, pq, dist, beta, packed);
    k_proc <<<512,  256, 0, stream>>>(packed, proc);
    k_final<<<2048, 256, 0, stream>>>(q, proc, (float*)d_out);
}